// Round 1
// baseline (148.310 us; speedup 1.0000x reference)
//
#include <hip/hip_runtime.h>
#include <cstddef>

#define NB   32768
#define MM   32
#define HH   64
#define NL   4
#define DIN  160

// packed weight layout (float4 units) in d_ws
#define PIN_N   (40*64)          // W_in  [k4][lane] : 2560
#define PENC_N  (NL*16*64)       // W_enc [l][k4][lane] : 4096
#define POUT_N  (16*32)          // W_out [k4][m] : 512
#define PACK_BYTES ((size_t)(PIN_N+PENC_N+POUT_N)*16)

#define E     8                  // elements per wave
#define WAVES 4
// per-wave LDS float offsets
#define FE   0                   // feats  [E][160]
#define HB   (E*160)             // h      [E][64]
#define WB   (E*160 + E*64)      // w      [E][33] (padded)
#define WSZ  (E*160 + E*64 + E*33)   // 2056 floats/wave

__global__ void pack_weights_kernel(const float* __restrict__ W_in,
                                    const float* __restrict__ W_enc,
                                    const float* __restrict__ W_out,
                                    float4* __restrict__ P) {
  const int stride = gridDim.x * blockDim.x;
  const int tid = blockIdx.x * blockDim.x + threadIdx.x;
  for (int i = tid; i < PIN_N; i += stride) {
    const int k4 = i >> 6, r = i & 63;
    const float* p = W_in + r * DIN + (k4 << 2);
    P[i] = make_float4(p[0], p[1], p[2], p[3]);
  }
  for (int i = tid; i < PENC_N; i += stride) {
    const int l = i >> 10, rem = i & 1023;
    const int k4 = rem >> 6, r = rem & 63;
    const float* p = W_enc + l * HH * HH + r * HH + (k4 << 2);
    P[PIN_N + i] = make_float4(p[0], p[1], p[2], p[3]);
  }
  for (int i = tid; i < POUT_N; i += stride) {
    const int k4 = i >> 5, m = i & 31;
    const float* p = W_out + m * HH + (k4 << 2);
    P[PIN_N + PENC_N + i] = make_float4(p[0], p[1], p[2], p[3]);
  }
}

template<bool PACKED>
__global__ __launch_bounds__(256)
void wls_fused(const float* __restrict__ x,
               const int* __restrict__ pad,
               const float* __restrict__ W_in,
               const float* __restrict__ b_in,
               const float* __restrict__ a_in,
               const float* __restrict__ W_enc,
               const float* __restrict__ b_enc,
               const float* __restrict__ a_enc,
               const float* __restrict__ W_out,
               const float* __restrict__ b_out,
               const float4* __restrict__ P,
               float* __restrict__ out) {
  __shared__ float lds[WAVES * WSZ];
  const int wave = threadIdx.x >> 6;
  const int lane = threadIdx.x & 63;
  float* S = lds + wave * WSZ;
  const int e0 = (blockIdx.x * WAVES + wave) * E;

  // ---- stage feats into LDS: feats[e][5m+j] = x[b][m][j], feats[e][5m+4] = !pad ----
  {
    const int m = lane >> 1;
    const int j = (lane & 1) << 1;
    #pragma unroll
    for (int e = 0; e < E; ++e) {
      const float2 v = *reinterpret_cast<const float2*>(x + (size_t)(e0 + e) * 128 + (lane << 1));
      S[FE + e * 160 + 5 * m + j]     = v.x;
      S[FE + e * 160 + 5 * m + j + 1] = v.y;
    }
    if (lane < MM) {
      #pragma unroll
      for (int e = 0; e < E; ++e) {
        const int pm = pad[(e0 + e) * MM + lane];
        S[FE + e * 160 + 5 * lane + 4] = pm ? 0.0f : 1.0f;
      }
    }
  }
  __syncthreads();

  // ---- input layer: h[lane] = prelu(W_in[lane,:] . feats + b_in[lane]) ----
  float h[E];
  {
    const float bi = b_in[lane];
    #pragma unroll
    for (int e = 0; e < E; ++e) h[e] = bi;
    for (int k4 = 0; k4 < 40; ++k4) {
      const float4 wv = PACKED ? P[k4 * 64 + lane]
                               : *reinterpret_cast<const float4*>(W_in + lane * DIN + (k4 << 2));
      #pragma unroll
      for (int e = 0; e < E; ++e) {
        const float4 f = *reinterpret_cast<const float4*>(&S[FE + e * 160 + (k4 << 2)]);
        h[e] = fmaf(wv.x, f.x, h[e]);
        h[e] = fmaf(wv.y, f.y, h[e]);
        h[e] = fmaf(wv.z, f.z, h[e]);
        h[e] = fmaf(wv.w, f.w, h[e]);
      }
    }
    const float a0 = a_in[0];
    #pragma unroll
    for (int e = 0; e < E; ++e) h[e] = (h[e] >= 0.0f) ? h[e] : a0 * h[e];
  }
  #pragma unroll
  for (int e = 0; e < E; ++e) S[HB + e * 64 + lane] = h[e];
  __syncthreads();

  // ---- encoder layers ----
  for (int l = 0; l < NL; ++l) {
    const float bi = b_enc[l * HH + lane];
    float acc[E];
    #pragma unroll
    for (int e = 0; e < E; ++e) acc[e] = bi;
    for (int k4 = 0; k4 < 16; ++k4) {
      const float4 wv = PACKED ? P[PIN_N + l * 1024 + k4 * 64 + lane]
                               : *reinterpret_cast<const float4*>(W_enc + l * HH * HH + lane * HH + (k4 << 2));
      #pragma unroll
      for (int e = 0; e < E; ++e) {
        const float4 f = *reinterpret_cast<const float4*>(&S[HB + e * 64 + (k4 << 2)]);
        acc[e] = fmaf(wv.x, f.x, acc[e]);
        acc[e] = fmaf(wv.y, f.y, acc[e]);
        acc[e] = fmaf(wv.z, f.z, acc[e]);
        acc[e] = fmaf(wv.w, f.w, acc[e]);
      }
    }
    const float al = a_enc[l];
    #pragma unroll
    for (int e = 0; e < E; ++e) acc[e] = (acc[e] >= 0.0f) ? acc[e] : al * acc[e];
    __syncthreads();            // all reads of old h complete
    #pragma unroll
    for (int e = 0; e < E; ++e) S[HB + e * 64 + lane] = acc[e];
    __syncthreads();
  }

  // ---- output layer: w[e][m]; lanes 0..31 -> e 0..3, lanes 32..63 -> e 4..7 ----
  {
    const int m  = lane & 31;
    const int eb = (lane >> 5) << 2;
    float acc[4];
    const float bo = b_out[m];
    #pragma unroll
    for (int j = 0; j < 4; ++j) acc[j] = bo;
    for (int k4 = 0; k4 < 16; ++k4) {
      const float4 wv = PACKED ? P[PIN_N + PENC_N + k4 * 32 + m]
                               : *reinterpret_cast<const float4*>(W_out + m * HH + (k4 << 2));
      #pragma unroll
      for (int j = 0; j < 4; ++j) {
        const float4 f = *reinterpret_cast<const float4*>(&S[HB + (eb + j) * 64 + (k4 << 2)]);
        acc[j] = fmaf(wv.x, f.x, acc[j]);
        acc[j] = fmaf(wv.y, f.y, acc[j]);
        acc[j] = fmaf(wv.z, f.z, acc[j]);
        acc[j] = fmaf(wv.w, f.w, acc[j]);
      }
    }
    #pragma unroll
    for (int j = 0; j < 4; ++j) S[WB + (eb + j) * 33 + m] = acc[j];
  }
  __syncthreads();

  // ---- epilogue: 4 lanes per element; G = A^T W^2 A (sym 4x4), c = A^T W^2 r ----
  if (lane < 32) {
    const int e = lane >> 2;
    const int p = lane & 3;
    float s[14];
    #pragma unroll
    for (int v = 0; v < 14; ++v) s[v] = 0.0f;
    #pragma unroll
    for (int t = 0; t < 8; ++t) {
      const int mm = (p << 3) + t;
      const float w  = S[WB + e * 33 + mm];
      const float r  =  S[FE + e * 160 + 5 * mm];
      const float a1 = -S[FE + e * 160 + 5 * mm + 1];
      const float a2 = -S[FE + e * 160 + 5 * mm + 2];
      const float a3 = -S[FE + e * 160 + 5 * mm + 3];
      const float ww = w * w;
      const float w1 = ww * a1, w2 = ww * a2, w3 = ww * a3;
      s[0] += w1 * a1;  s[1] += w1 * a2;  s[2] += w1 * a3;  s[3] += w1;
      s[4] += w2 * a2;  s[5] += w2 * a3;  s[6] += w2;
      s[7] += w3 * a3;  s[8] += w3;
      s[9] += ww;
      s[10] += w1 * r;  s[11] += w2 * r;  s[12] += w3 * r;  s[13] += ww * r;
    }
    #pragma unroll
    for (int v = 0; v < 14; ++v) {
      s[v] += __shfl_xor(s[v], 1);
      s[v] += __shfl_xor(s[v], 2);
    }
    // augmented [G | c], Gaussian elimination (G is SPD -> no pivoting needed)
    float Mt[4][5] = {
      {s[0], s[1], s[2], s[3], s[10]},
      {s[1], s[4], s[5], s[6], s[11]},
      {s[2], s[5], s[7], s[8], s[12]},
      {s[3], s[6], s[8], s[9], s[13]},
    };
    #pragma unroll
    for (int k = 0; k < 3; ++k) {
      const float inv = 1.0f / Mt[k][k];
      #pragma unroll
      for (int r2 = k + 1; r2 < 4; ++r2) {
        const float fk = Mt[r2][k] * inv;
        #pragma unroll
        for (int c = k + 1; c < 5; ++c) Mt[r2][c] -= fk * Mt[k][c];
      }
    }
    const float th3 = Mt[3][4] / Mt[3][3];
    const float th2 = (Mt[2][4] - Mt[2][3] * th3) / Mt[2][2];
    const float th1 = (Mt[1][4] - Mt[1][3] * th3 - Mt[1][2] * th2) / Mt[1][1];
    const float th0 = (Mt[0][4] - Mt[0][3] * th3 - Mt[0][2] * th2 - Mt[0][1] * th1) / Mt[0][0];
    if (p == 0) {
      *reinterpret_cast<float4*>(out + (size_t)(e0 + e) * 4) = make_float4(th0, th1, th2, th3);
    }
  }
}

extern "C" void kernel_launch(void* const* d_in, const int* in_sizes, int n_in,
                              void* d_out, int out_size, void* d_ws, size_t ws_size,
                              hipStream_t stream) {
  const float* x     = (const float*)d_in[0];
  const int*   pad   = (const int*)d_in[1];
  const float* W_in  = (const float*)d_in[2];
  const float* b_in  = (const float*)d_in[3];
  const float* a_in  = (const float*)d_in[4];
  const float* W_enc = (const float*)d_in[5];
  const float* b_enc = (const float*)d_in[6];
  const float* a_enc = (const float*)d_in[7];
  const float* W_out = (const float*)d_in[8];
  const float* b_out = (const float*)d_in[9];
  float* out = (float*)d_out;
  float4* P = (float4*)d_ws;

  const int grid = NB / (WAVES * E);  // 1024 blocks x 256 threads, 8 elems/wave

  if (ws_size >= PACK_BYTES) {
    pack_weights_kernel<<<64, 256, 0, stream>>>(W_in, W_enc, W_out, P);
    wls_fused<true><<<grid, 256, 0, stream>>>(x, pad, W_in, b_in, a_in, W_enc,
                                              b_enc, a_enc, W_out, b_out, P, out);
  } else {
    wls_fused<false><<<grid, 256, 0, stream>>>(x, pad, W_in, b_in, a_in, W_enc,
                                               b_enc, a_enc, W_out, b_out, P, out);
  }
}

// Round 2
// 94.766 us; speedup vs baseline: 1.5650x; 1.5650x over previous
//
#include <hip/hip_runtime.h>
#include <cstddef>
#include <cstdint>

typedef float f32x4 __attribute__((ext_vector_type(4)));
typedef __bf16 bf16x8 __attribute__((ext_vector_type(8)));

#define MFMA_B16(a, b, c) __builtin_amdgcn_mfma_f32_16x16x32_bf16(a, b, c, 0, 0, 0)

// ---- d_ws fragment layout (bytes) ----
// L0  : [kt=4][nt=4][pl=2][lane=64][16B]  = 32768   (W' : W_in x-part, K=128)
// WV  : [nt=4][pl=2][lane][16B]           =  8192   (W_in valid-part, K=32)
// ENC : [l=4][kt=2][nt=4][pl=2][lane][16B]= 65536
// OUT : [kt=2][nt=2][pl=2][lane][16B]     =  8192
#define OFF_L0   0u
#define OFF_WV   32768u
#define OFF_ENC  40960u
#define OFF_OUT  106496u
#define WS_NEED  114688u

// ---- LDS layout (per block, 64 elements) ----
#define XB_OFF   0        // x rows  [64][128] f32, 512B rows, swizzled   (32768 B)
#define AH_OFF   32768    // act hi  [64][64] bf16, 128B rows, swizzled   ( 8192 B)
#define AL_OFF   40960    // act lo  (pad/valid plane overlays this)      ( 8192 B)
#define WG_OFF   49152    // weight stage buffer (16384 B); wsolve [64][33] f32 overlays after last use

__device__ __forceinline__ int xadr(int e, int b) { return (e << 9) | (b ^ ((e & 7) << 4)); }
__device__ __forceinline__ int aadr(int e, int b) { return (e << 7) | (b ^ ((e & 7) << 4)); }

// =====================  weight prep: fp32 -> bf16 hi/lo B-fragments  =====================
__global__ __launch_bounds__(256)
void prep_frags(const float* __restrict__ W_in, const float* __restrict__ W_enc,
                const float* __restrict__ W_out, unsigned* __restrict__ P) {
  const int idx = blockIdx.x * 256 + threadIdx.x;   // one u32 (2 bf16) per thread
  if (idx >= 28672) return;
  const int t = idx & 3;
  const int lane = (idx >> 2) & 63;
  const int g = lane >> 4, c = lane & 15;
  const int j0 = t << 1;
  int pl;
  float w0, w1;
  if (idx < 8192) {                       // L0 x-part: B[k][n], n = 4c+nt, k = kt*32+8g+j
    const int rest = idx >> 8;
    pl = rest & 1;
    const int nt = (rest >> 1) & 3;
    const int kt = rest >> 3;
    const int n = 4 * c + nt;
    const int k = kt * 32 + g * 8 + j0;
    const int m = k >> 2, q = k & 3;      // W'[n][k] = W_in[n][5m+q]
    w0 = W_in[n * 160 + 5 * m + q];
    w1 = W_in[n * 160 + 5 * m + q + 1];   // j0 even -> q in {0,2}, q+1 same m
  } else if (idx < 10240) {               // WV valid-part: k = m
    const int rest = (idx - 8192) >> 8;
    pl = rest & 1;
    const int nt = rest >> 1;
    const int n = 4 * c + nt;
    const int m = g * 8 + j0;
    w0 = W_in[n * 160 + 5 * m + 4];
    w1 = W_in[n * 160 + 5 * (m + 1) + 4];
  } else if (idx < 26624) {               // ENC
    const int rel = idx - 10240;
    const int l = rel >> 12;
    const int rest = (rel & 4095) >> 8;
    pl = rest & 1;
    const int nt = (rest >> 1) & 3;
    const int kt = rest >> 3;
    const int n = 4 * c + nt;
    const int k = kt * 32 + g * 8 + j0;
    w0 = W_enc[(l * 64 + n) * 64 + k];
    w1 = W_enc[(l * 64 + n) * 64 + k + 1];
  } else {                                // OUT (plain cols m = 16nt+c)
    const int rel = idx - 26624;
    const int rest = rel >> 8;
    pl = rest & 1;
    const int nt = (rest >> 1) & 1;
    const int kt = rest >> 2;
    const int mcol = 16 * nt + c;
    const int k = kt * 32 + g * 8 + j0;
    w0 = W_out[mcol * 64 + k];
    w1 = W_out[mcol * 64 + k + 1];
  }
  unsigned short u0, u1;
  if (pl == 0) {
    u0 = __builtin_bit_cast(unsigned short, (__bf16)w0);
    u1 = __builtin_bit_cast(unsigned short, (__bf16)w1);
  } else {
    const __bf16 h0 = (__bf16)w0, h1 = (__bf16)w1;
    u0 = __builtin_bit_cast(unsigned short, (__bf16)(w0 - (float)h0));
    u1 = __builtin_bit_cast(unsigned short, (__bf16)(w1 - (float)h1));
  }
  P[idx] = (unsigned)u0 | ((unsigned)u1 << 16);
}

// =====================  fused MLP (split-bf16 MFMA) + WLS solve  =====================
__global__ __launch_bounds__(256, 2)
void wls_mfma(const float* __restrict__ x, const int* __restrict__ pad,
              const float* __restrict__ b_in, const float* __restrict__ a_in,
              const float* __restrict__ b_enc, const float* __restrict__ a_enc,
              const float* __restrict__ b_out, const char* __restrict__ wf,
              float* __restrict__ out) {
  __shared__ __align__(16) unsigned char smem[65536];
  const int tid = threadIdx.x;
  const int wave = tid >> 6, lane = tid & 63;
  const int g = lane >> 4, c = lane & 15;
  const int eb = blockIdx.x << 6;          // 64 elements per block
  const int ew = eb + (wave << 4);         // this wave's first element

  // ---- stage x rows (coalesced 1KB/round, swizzled LDS writes) ----
  {
    float4 xv[8];
    const char* src = (const char*)x + (size_t)ew * 512 + lane * 16;
    #pragma unroll
    for (int i = 0; i < 8; ++i) xv[i] = *(const float4*)(src + i * 1024);
    #pragma unroll
    for (int i = 0; i < 8; ++i) {
      const int off = i * 1024 + lane * 16;
      const int e = (wave << 4) + (off >> 9);
      *(float4*)(smem + XB_OFF + xadr(e, off & 511)) = xv[i];
    }
  }
  // ---- stage valid = !pad as exact bf16 into AL plane (pitch 128B) ----
  {
    #pragma unroll
    for (int t = 0; t < 2; ++t) {
      const int el = lane >> 2;
      const int mq = (lane & 3) + (t << 2);
      const int4 pv = *(const int4*)(pad + (size_t)(ew + el) * 32 + (mq << 2));
      const unsigned ONE = 0x3F80u;  // bf16(1.0)
      const unsigned u0 = (pv.x ? 0u : ONE) | ((pv.y ? 0u : ONE) << 16);
      const unsigned u1 = (pv.z ? 0u : ONE) | ((pv.w ? 0u : ONE) << 16);
      const int e = (wave << 4) + el;
      *(uint2*)(smem + AL_OFF + aadr(e, mq << 3)) = make_uint2(u0, u1);
    }
  }

  auto copy_wgt = [&](unsigned goff, int nbytes) {
    const int share = nbytes >> 2;
    const char* s = wf + goff + wave * share + lane * 16;
    unsigned char* d = smem + WG_OFF + wave * share + lane * 16;
    if (nbytes == 16384) {
      float4 t0 = *(const float4*)(s);
      float4 t1 = *(const float4*)(s + 1024);
      float4 t2 = *(const float4*)(s + 2048);
      float4 t3 = *(const float4*)(s + 3072);
      *(float4*)(d) = t0;           *(float4*)(d + 1024) = t1;
      *(float4*)(d + 2048) = t2;    *(float4*)(d + 3072) = t3;
    } else {
      float4 t0 = *(const float4*)(s);
      float4 t1 = *(const float4*)(s + 1024);
      *(float4*)(d) = t0;           *(float4*)(d + 1024) = t1;
    }
  };
  auto bfrag = [&](int slot) -> bf16x8 {
    return *(const bf16x8*)(smem + WG_OFF + slot * 1024 + lane * 16);
  };
  auto xfrag = [&](int kt, bf16x8& ah, bf16x8& al) {
    const int e = (wave << 4) + c;
    const int b0 = kt * 128 + g * 32;
    const float4 v0 = *(const float4*)(smem + XB_OFF + xadr(e, b0));
    const float4 v1 = *(const float4*)(smem + XB_OFF + xadr(e, b0 + 16));
    const float vv[8] = {v0.x, v0.y, v0.z, v0.w, v1.x, v1.y, v1.z, v1.w};
    #pragma unroll
    for (int j = 0; j < 8; ++j) {
      const __bf16 h = (__bf16)vv[j];
      ah[j] = h;
      al[j] = (__bf16)(vv[j] - (float)h);
    }
  };
  // prelu -> split bf16 -> write act planes (n = 4c+nt permutation => contiguous 8B)
  auto act_store = [&](f32x4* a4, float alpha) {
    #pragma unroll
    for (int r = 0; r < 4; ++r) {
      const int e = (wave << 4) + (g << 2) + r;
      unsigned hu[2], lu[2];
      #pragma unroll
      for (int q = 0; q < 2; ++q) {
        unsigned short hb[2], lb[2];
        #pragma unroll
        for (int s2 = 0; s2 < 2; ++s2) {
          float h = a4[2 * q + s2][r];
          h = (h >= 0.0f) ? h : alpha * h;
          const __bf16 hh = (__bf16)h;
          const __bf16 ll = (__bf16)(h - (float)hh);
          hb[s2] = __builtin_bit_cast(unsigned short, hh);
          lb[s2] = __builtin_bit_cast(unsigned short, ll);
        }
        hu[q] = (unsigned)hb[0] | ((unsigned)hb[1] << 16);
        lu[q] = (unsigned)lb[0] | ((unsigned)lb[1] << 16);
      }
      *(uint2*)(smem + AH_OFF + aadr(e, c * 8)) = make_uint2(hu[0], hu[1]);
      *(uint2*)(smem + AL_OFF + aadr(e, c * 8)) = make_uint2(lu[0], lu[1]);
    }
  };

  // ---- layer 0: x-part (K=128, staged in 2 halves) + valid-part (K=32) ----
  f32x4 acc[4];
  #pragma unroll
  for (int nt = 0; nt < 4; ++nt) {
    const float bv = b_in[4 * c + nt];
    f32x4 a = {bv, bv, bv, bv};
    acc[nt] = a;
  }
  copy_wgt(OFF_L0, 16384);
  __syncthreads();
  #pragma unroll
  for (int half = 0; half < 2; ++half) {
    if (half) {
      __syncthreads();
      copy_wgt(OFF_L0 + 16384, 16384);
      __syncthreads();
    }
    #pragma unroll
    for (int ktl = 0; ktl < 2; ++ktl) {
      bf16x8 ah, al;
      xfrag(half * 2 + ktl, ah, al);
      #pragma unroll
      for (int nt = 0; nt < 4; ++nt) {
        const bf16x8 bh = bfrag((ktl * 4 + nt) * 2);
        const bf16x8 bl = bfrag((ktl * 4 + nt) * 2 + 1);
        acc[nt] = MFMA_B16(ah, bh, acc[nt]);
        acc[nt] = MFMA_B16(ah, bl, acc[nt]);
        acc[nt] = MFMA_B16(al, bh, acc[nt]);
      }
    }
  }
  __syncthreads();
  copy_wgt(OFF_WV, 8192);
  __syncthreads();
  {
    const int e = (wave << 4) + c;
    const bf16x8 va = *(const bf16x8*)(smem + AL_OFF + aadr(e, g * 16));  // exact bf16
    #pragma unroll
    for (int nt = 0; nt < 4; ++nt) {
      const bf16x8 bh = bfrag(nt * 2);
      const bf16x8 bl = bfrag(nt * 2 + 1);
      acc[nt] = MFMA_B16(va, bh, acc[nt]);
      acc[nt] = MFMA_B16(va, bl, acc[nt]);
    }
  }
  act_store(acc, a_in[0]);

  // ---- encoder layers ----
  #pragma unroll
  for (int l = 0; l < 4; ++l) {
    __syncthreads();
    copy_wgt(OFF_ENC + l * 16384, 16384);
    __syncthreads();
    bf16x8 ah0, ah1, al0, al1;
    {
      const int e = (wave << 4) + c;
      ah0 = *(const bf16x8*)(smem + AH_OFF + aadr(e, g * 16));
      ah1 = *(const bf16x8*)(smem + AH_OFF + aadr(e, 64 + g * 16));
      al0 = *(const bf16x8*)(smem + AL_OFF + aadr(e, g * 16));
      al1 = *(const bf16x8*)(smem + AL_OFF + aadr(e, 64 + g * 16));
    }
    f32x4 a2[4];
    #pragma unroll
    for (int nt = 0; nt < 4; ++nt) {
      const float bv = b_enc[l * 64 + 4 * c + nt];
      f32x4 a = {bv, bv, bv, bv};
      a2[nt] = a;
    }
    #pragma unroll
    for (int kt = 0; kt < 2; ++kt) {
      const bf16x8 Ah = kt ? ah1 : ah0;
      const bf16x8 Al = kt ? al1 : al0;
      #pragma unroll
      for (int nt = 0; nt < 4; ++nt) {
        const bf16x8 bh = bfrag((kt * 4 + nt) * 2);
        const bf16x8 bl = bfrag((kt * 4 + nt) * 2 + 1);
        a2[nt] = MFMA_B16(Ah, bh, a2[nt]);
        a2[nt] = MFMA_B16(Ah, bl, a2[nt]);
        a2[nt] = MFMA_B16(Al, bh, a2[nt]);
      }
    }
    act_store(a2, a_enc[l]);
  }

  // ---- output layer (m = 16nt + c, no perm) ----
  __syncthreads();
  copy_wgt(OFF_OUT, 8192);
  __syncthreads();
  bf16x8 oah[2], oal[2], obh[4], obl[4];
  {
    const int e = (wave << 4) + c;
    #pragma unroll
    for (int kt = 0; kt < 2; ++kt) {
      oah[kt] = *(const bf16x8*)(smem + AH_OFF + aadr(e, kt * 64 + g * 16));
      oal[kt] = *(const bf16x8*)(smem + AL_OFF + aadr(e, kt * 64 + g * 16));
      #pragma unroll
      for (int nt = 0; nt < 2; ++nt) {
        obh[kt * 2 + nt] = bfrag((kt * 2 + nt) * 2);
        obl[kt * 2 + nt] = bfrag((kt * 2 + nt) * 2 + 1);
      }
    }
  }
  __syncthreads();   // all waves done with wgt buffer -> reuse as wsolve
  f32x4 aw[2];
  #pragma unroll
  for (int nt = 0; nt < 2; ++nt) {
    const float bv = b_out[16 * nt + c];
    f32x4 a = {bv, bv, bv, bv};
    aw[nt] = a;
  }
  #pragma unroll
  for (int kt = 0; kt < 2; ++kt) {
    #pragma unroll
    for (int nt = 0; nt < 2; ++nt) {
      aw[nt] = MFMA_B16(oah[kt], obh[kt * 2 + nt], aw[nt]);
      aw[nt] = MFMA_B16(oah[kt], obl[kt * 2 + nt], aw[nt]);
      aw[nt] = MFMA_B16(oal[kt], obh[kt * 2 + nt], aw[nt]);
    }
  }
  {
    float* ws = (float*)(smem + WG_OFF);
    #pragma unroll
    for (int nt = 0; nt < 2; ++nt)
      #pragma unroll
      for (int r = 0; r < 4; ++r)
        ws[((wave << 4) + (g << 2) + r) * 33 + 16 * nt + c] = aw[nt][r];
  }

  // ---- epilogue: G = A^T W^2 A (4x4 SPD), c = A^T W^2 r; 4 lanes per element ----
  {
    const int el = lane >> 2;
    const int p = lane & 3;
    const int e = (wave << 4) + el;
    const float* ws = (const float*)(smem + WG_OFF);
    float s[14];
    #pragma unroll
    for (int v = 0; v < 14; ++v) s[v] = 0.0f;
    #pragma unroll
    for (int t = 0; t < 8; ++t) {
      const int mm = (p << 3) + t;
      const float w = ws[e * 33 + mm];
      const float4 xv = *(const float4*)(smem + XB_OFF + xadr(e, mm << 4));
      const float r = xv.x;
      const float a1 = -xv.y, a2 = -xv.z, a3 = -xv.w;
      const float ww = w * w;
      const float w1 = ww * a1, w2 = ww * a2, w3 = ww * a3;
      s[0] += w1 * a1;  s[1] += w1 * a2;  s[2] += w1 * a3;  s[3] += w1;
      s[4] += w2 * a2;  s[5] += w2 * a3;  s[6] += w2;
      s[7] += w3 * a3;  s[8] += w3;
      s[9] += ww;
      s[10] += w1 * r;  s[11] += w2 * r;  s[12] += w3 * r;  s[13] += ww * r;
    }
    #pragma unroll
    for (int v = 0; v < 14; ++v) {
      s[v] += __shfl_xor(s[v], 1);
      s[v] += __shfl_xor(s[v], 2);
    }
    float Mt[4][5] = {
      {s[0], s[1], s[2], s[3], s[10]},
      {s[1], s[4], s[5], s[6], s[11]},
      {s[2], s[5], s[7], s[8], s[12]},
      {s[3], s[6], s[8], s[9], s[13]},
    };
    #pragma unroll
    for (int k = 0; k < 3; ++k) {
      const float inv = 1.0f / Mt[k][k];
      #pragma unroll
      for (int r2 = k + 1; r2 < 4; ++r2) {
        const float fk = Mt[r2][k] * inv;
        #pragma unroll
        for (int cc = k + 1; cc < 5; ++cc) Mt[r2][cc] -= fk * Mt[k][cc];
      }
    }
    const float th3 = Mt[3][4] / Mt[3][3];
    const float th2 = (Mt[2][4] - Mt[2][3] * th3) / Mt[2][2];
    const float th1 = (Mt[1][4] - Mt[1][3] * th3 - Mt[1][2] * th2) / Mt[1][1];
    const float th0 = (Mt[0][4] - Mt[0][3] * th3 - Mt[0][2] * th2 - Mt[0][1] * th1) / Mt[0][0];
    if (p == 0) {
      *(float4*)(out + (size_t)(eb + (wave << 4) + el) * 4) = make_float4(th0, th1, th2, th3);
    }
  }
}

extern "C" void kernel_launch(void* const* d_in, const int* in_sizes, int n_in,
                              void* d_out, int out_size, void* d_ws, size_t ws_size,
                              hipStream_t stream) {
  const float* x     = (const float*)d_in[0];
  const int*   pad   = (const int*)d_in[1];
  const float* W_in  = (const float*)d_in[2];
  const float* b_in  = (const float*)d_in[3];
  const float* a_in  = (const float*)d_in[4];
  const float* W_enc = (const float*)d_in[5];
  const float* b_enc = (const float*)d_in[6];
  const float* a_enc = (const float*)d_in[7];
  const float* W_out = (const float*)d_in[8];
  const float* b_out = (const float*)d_in[9];
  float* out = (float*)d_out;

  prep_frags<<<112, 256, 0, stream>>>(W_in, W_enc, W_out, (unsigned*)d_ws);
  wls_mfma<<<512, 256, 0, stream>>>(x, pad, b_in, a_in, b_enc, a_enc, b_out,
                                    (const char*)d_ws, out);
}